// Round 1
// baseline (377.409 us; speedup 1.0000x reference)
//
#include <hip/hip_runtime.h>

namespace {

constexpr int   HG  = 1440;
constexpr int   WG  = 1440;
constexpr int   HWG = HG * WG;                       // 2,073,600 cells per batch
constexpr float PIL = 0.075f;
constexpr float XOFF = (float)(0.075 / 2.0 - 54.0);  // -53.9625, rounded once from f64
constexpr float YOFF = XOFF;

constexpr int SCAN_T    = 256;
constexpr int SCAN_WPT  = 4;
constexpr int SCAN_CHUNK = SCAN_T * SCAN_WPT;        // 1024 words / block

// ---------------- scatter: mark occupied cells in a bitmask -----------------
__global__ __launch_bounds__(256) void scatter_k(
    const int* __restrict__ xy, const int* __restrict__ cnt, int batch, int N,
    unsigned int* __restrict__ bits)
{
    int i = blockIdx.x * 256 + threadIdx.x;
    if (i >= N) return;
    int2 p = reinterpret_cast<const int2*>(xy)[i];   // p.x = x, p.y = y
    int b = 0, acc = 0;
    for (int k = 0; k < batch - 1; ++k) { acc += cnt[k]; b += (i >= acc) ? 1 : 0; }
    int flat = (b * HG + p.y) * WG + p.x;
    atomicOr(&bits[flat >> 5], 1u << (flat & 31));
}

// ---------------- scan pass A: per-block popcount sums ----------------------
__global__ __launch_bounds__(SCAN_T) void scan_a(
    const unsigned int* __restrict__ bits, int nwords,
    unsigned int* __restrict__ bsums)
{
    int t = threadIdx.x;
    int base = blockIdx.x * SCAN_CHUNK + t * SCAN_WPT;
    unsigned int s = 0;
    if (base + SCAN_WPT <= nwords) {
        uint4 q = *reinterpret_cast<const uint4*>(bits + base);
        s = __popc(q.x) + __popc(q.y) + __popc(q.z) + __popc(q.w);
    } else {
        for (int k = 0; k < SCAN_WPT; ++k)
            if (base + k < nwords) s += __popc(bits[base + k]);
    }
#pragma unroll
    for (int d = 32; d > 0; d >>= 1) s += __shfl_down(s, d);
    __shared__ unsigned int red[SCAN_T / 64];
    if ((t & 63) == 0) red[t >> 6] = s;
    __syncthreads();
    if (t == 0) {
        unsigned int tot = 0;
        for (int w = 0; w < SCAN_T / 64; ++w) tot += red[w];
        bsums[blockIdx.x] = tot;
    }
}

// ---------------- scan pass B: exclusive scan of block sums (nb <= 256) -----
__global__ __launch_bounds__(SCAN_T) void scan_b(unsigned int* bsums, int nb)
{
    int t = threadIdx.x;
    unsigned int v = (t < nb) ? bsums[t] : 0u;
    unsigned int x = v;
#pragma unroll
    for (int d = 1; d < 64; d <<= 1) {
        unsigned int y = __shfl_up(x, d);
        if ((t & 63) >= d) x += y;
    }
    __shared__ unsigned int ws[SCAN_T / 64];
    if ((t & 63) == 63) ws[t >> 6] = x;
    __syncthreads();
    unsigned int off = 0;
    for (int w = 0; w < (t >> 6); ++w) off += ws[w];
    if (t < nb) bsums[t] = off + x - v;   // exclusive
}

// ------- scan pass C: word-level exclusive scan + pillar_indices emit -------
__global__ __launch_bounds__(SCAN_T) void scan_c(
    const unsigned int* __restrict__ bits, int nwords,
    const unsigned int* __restrict__ bsums,
    unsigned int* __restrict__ wordscan,
    float* __restrict__ pillar_out)
{
    int t = threadIdx.x;
    int base = blockIdx.x * SCAN_CHUNK + t * SCAN_WPT;
    unsigned int w[SCAN_WPT];
    if (base + SCAN_WPT <= nwords) {
        uint4 q = *reinterpret_cast<const uint4*>(bits + base);
        w[0] = q.x; w[1] = q.y; w[2] = q.z; w[3] = q.w;
    } else {
        for (int k = 0; k < SCAN_WPT; ++k)
            w[k] = (base + k < nwords) ? bits[base + k] : 0u;
    }
    unsigned int s = 0;
#pragma unroll
    for (int k = 0; k < SCAN_WPT; ++k) s += __popc(w[k]);
    unsigned int x = s;
#pragma unroll
    for (int d = 1; d < 64; d <<= 1) {
        unsigned int y = __shfl_up(x, d);
        if ((t & 63) >= d) x += y;
    }
    __shared__ unsigned int ws[SCAN_T / 64];
    if ((t & 63) == 63) ws[t >> 6] = x;
    __syncthreads();
    unsigned int run = bsums[blockIdx.x] + x - s;     // exclusive within grid
    for (int wv = 0; wv < (t >> 6); ++wv) run += ws[wv];
#pragma unroll
    for (int k = 0; k < SCAN_WPT; ++k) {
        int widx = base + k;
        if (widx >= nwords) break;
        wordscan[widx] = run;
        unsigned int bw = w[k];
        while (bw) {
            int bit = __builtin_ctz(bw);
            bw &= bw - 1u;
            int cell = (widx << 5) + bit;
            int bidx = cell / HWG;
            int rem  = cell - bidx * HWG;
            int hy   = rem / WG;
            int wx   = rem - hy * WG;
            float* row = pillar_out + 3ull * run;
            row[0] = (float)bidx;
            row[1] = (float)hy;
            row[2] = (float)wx;
            ++run;
        }
    }
}

// ---------------- per-point: pid gather + feature assembly ------------------
constexpr int PT_T = 256;
__global__ __launch_bounds__(PT_T) void point_k(
    const int* __restrict__ xy, const int* __restrict__ cnt, int batch,
    const float* __restrict__ feats, int N,
    const unsigned int* __restrict__ bits,
    const unsigned int* __restrict__ wordscan,
    float* __restrict__ ppi_out, float* __restrict__ feat_out)
{
    __shared__ float lds[PT_T][19];   // pad 18 -> 19: gcd(19,32)=1, conflict-free
    int t = threadIdx.x;
    int blockBase = blockIdx.x * PT_T;
    int i = blockBase + t;
    int nvalid = N - blockBase; if (nvalid > PT_T) nvalid = PT_T;

    if (t < nvalid) {
        int2 p = reinterpret_cast<const int2*>(xy)[i];
        int b = 0, acc = 0;
        for (int k = 0; k < batch - 1; ++k) { acc += cnt[k]; b += (i >= acc) ? 1 : 0; }
        int flat = (b * HG + p.y) * WG + p.x;
        int widx = flat >> 5, bit = flat & 31;
        unsigned int pid = wordscan[widx] + __popc(bits[widx] & ((1u << bit) - 1u));
        ppi_out[i] = (float)pid;

        const float4* fr = reinterpret_cast<const float4*>(feats + 16ll * i);
        float4 f0 = fr[0], f1 = fr[1], f2 = fr[2], f3 = fr[3];
        float cx = (float)p.x * PIL + XOFF;
        float cy = (float)p.y * PIL + YOFF;
        lds[t][0]  = f0.x - cx;  lds[t][1]  = f0.y - cy;
        lds[t][2]  = f0.x;  lds[t][3]  = f0.y;  lds[t][4]  = f0.z;  lds[t][5]  = f0.w;
        lds[t][6]  = f1.x;  lds[t][7]  = f1.y;  lds[t][8]  = f1.z;  lds[t][9]  = f1.w;
        lds[t][10] = f2.x;  lds[t][11] = f2.y;  lds[t][12] = f2.z;  lds[t][13] = f2.w;
        lds[t][14] = f3.x;  lds[t][15] = f3.y;  lds[t][16] = f3.z;  lds[t][17] = f3.w;
    }
    __syncthreads();

    // coalesced write-out of nvalid*18 contiguous floats
    float* dst = feat_out + 18ll * blockBase;
    int total = nvalid * 18;
    for (int j = t; j < total; j += PT_T) {
        int p = j / 18;
        int c = j - p * 18;
        dst[j] = lds[p][c];
    }
}

} // anonymous namespace

extern "C" void kernel_launch(void* const* d_in, const int* in_sizes, int n_in,
                              void* d_out, int out_size, void* d_ws, size_t ws_size,
                              hipStream_t stream)
{
    const int*   xy    = (const int*)d_in[0];
    const int*   cnt   = (const int*)d_in[1];
    const float* feats = (const float*)d_in[2];

    int N     = in_sizes[0] / 2;
    int batch = in_sizes[1];
    long long ncells = (long long)batch * HWG;       // HWG % 32 == 0
    int nwords = (int)(ncells / 32);                 // 259,200 for batch=4
    // out_size = 3P + N + 18N  ->  P
    long long P = (out_size - 19ll * N) / 3;

    unsigned int* bits     = (unsigned int*)d_ws;
    unsigned int* wordscan = bits + nwords;
    unsigned int* bsums    = wordscan + nwords;

    float* pillar_out = (float*)d_out;
    float* ppi_out    = pillar_out + 3ll * P;
    float* feat_out   = ppi_out + N;

    hipMemsetAsync(bits, 0, (size_t)nwords * sizeof(unsigned int), stream);

    int nb_pts = (N + 255) / 256;
    scatter_k<<<nb_pts, 256, 0, stream>>>(xy, cnt, batch, N, bits);

    int nb_scan = (nwords + SCAN_CHUNK - 1) / SCAN_CHUNK;   // 254 (<256 for scan_b)
    scan_a<<<nb_scan, SCAN_T, 0, stream>>>(bits, nwords, bsums);
    scan_b<<<1, SCAN_T, 0, stream>>>(bsums, nb_scan);
    scan_c<<<nb_scan, SCAN_T, 0, stream>>>(bits, nwords, bsums, wordscan, pillar_out);

    point_k<<<nb_pts, PT_T, 0, stream>>>(xy, cnt, batch, feats, N, bits, wordscan,
                                         ppi_out, feat_out);
}

// Round 3
// 357.672 us; speedup vs baseline: 1.0552x; 1.0552x over previous
//
#include <hip/hip_runtime.h>

namespace {

typedef float f32x4 __attribute__((ext_vector_type(4)));

constexpr int   HG  = 1440;
constexpr int   WG  = 1440;
constexpr int   HWG = HG * WG;                       // 2,073,600 cells per batch
constexpr float PIL = 0.075f;
constexpr float XOFF = (float)(0.075 / 2.0 - 54.0);  // -53.9625
constexpr float YOFF = XOFF;

constexpr int SCAN_T    = 256;
constexpr int SCAN_WPT  = 4;
constexpr int SCAN_CHUNK = SCAN_T * SCAN_WPT;        // 1024 words / block

// pack 4 occupancy bytes (each 0 or 1, little-endian in u) into a nibble:
// byte j -> bit j.  No carries: all partial products land on distinct bits.
__device__ inline unsigned nib4(unsigned u) {
    return (u * 0x01020408u) >> 24 & 0xFu;
}
__device__ inline unsigned pack_word(uint4 a, uint4 b) {
    return  nib4(a.x)        | nib4(a.y) << 4  | nib4(a.z) << 8  | nib4(a.w) << 12
          | nib4(b.x) << 16  | nib4(b.y) << 20 | nib4(b.z) << 24 | nib4(b.w) << 28;
}

// ------------- scatter: mark occupied cells with plain byte stores ----------
// No atomics: racing stores write the same value (1); L2 dirty-byte masks
// merge partial lines across XCDs safely.
__global__ __launch_bounds__(256) void pqag_scatter(
    const int* __restrict__ xy, const int* __restrict__ cnt, int batch, int N,
    unsigned char* __restrict__ bytemap)
{
    int i = blockIdx.x * 256 + threadIdx.x;
    if (i >= N) return;
    int2 p = reinterpret_cast<const int2*>(xy)[i];
    int b = 0, acc = 0;
    for (int k = 0; k < batch - 1; ++k) { acc += cnt[k]; b += (i >= acc) ? 1 : 0; }
    int flat = (b * HG + p.y) * WG + p.x;
    bytemap[flat] = 1;
}

// ------------- scan pass A: per-block occupied-cell counts ------------------
__global__ __launch_bounds__(SCAN_T) void pqag_scan_a(
    const unsigned char* __restrict__ bytemap, int nwords,
    unsigned int* __restrict__ bsums)
{
    int t = threadIdx.x;
    int wbase = blockIdx.x * SCAN_CHUNK + t * SCAN_WPT;
    unsigned int s = 0;
    if (wbase + SCAN_WPT <= nwords) {
        const uint4* q = reinterpret_cast<const uint4*>(bytemap) + 2ll * wbase;
#pragma unroll
        for (int k = 0; k < 2 * SCAN_WPT; ++k) {
            uint4 v = q[k];                 // bytes are 0/1 -> popc == count
            s += __popc(v.x) + __popc(v.y) + __popc(v.z) + __popc(v.w);
        }
    } else {
        for (int w = wbase; w < nwords && w < wbase + SCAN_WPT; ++w)
            for (int j = 0; j < 32; ++j) s += bytemap[32 * w + j];
    }
#pragma unroll
    for (int d = 32; d > 0; d >>= 1) s += __shfl_down(s, d);
    __shared__ unsigned int red[SCAN_T / 64];
    if ((t & 63) == 0) red[t >> 6] = s;
    __syncthreads();
    if (t == 0) {
        unsigned int tot = 0;
        for (int w = 0; w < SCAN_T / 64; ++w) tot += red[w];
        bsums[blockIdx.x] = tot;
    }
}

// ------------- scan pass B: exclusive scan of block sums (nb <= 256) --------
__global__ __launch_bounds__(SCAN_T) void pqag_scan_b(unsigned int* bsums, int nb)
{
    int t = threadIdx.x;
    unsigned int v = (t < nb) ? bsums[t] : 0u;
    unsigned int x = v;
#pragma unroll
    for (int d = 1; d < 64; d <<= 1) {
        unsigned int y = __shfl_up(x, d);
        if ((t & 63) >= d) x += y;
    }
    __shared__ unsigned int ws[SCAN_T / 64];
    if ((t & 63) == 63) ws[t >> 6] = x;
    __syncthreads();
    unsigned int off = 0;
    for (int w = 0; w < (t >> 6); ++w) off += ws[w];
    if (t < nb) bsums[t] = off + x - v;   // exclusive
}

// ------------- scan pass C: build bit words + word-level exclusive scan -----
__global__ __launch_bounds__(SCAN_T) void pqag_scan_c(
    const unsigned char* __restrict__ bytemap, int nwords,
    const unsigned int* __restrict__ bsums,
    unsigned int* __restrict__ bits,
    unsigned int* __restrict__ wordscan)
{
    int t = threadIdx.x;
    int wbase = blockIdx.x * SCAN_CHUNK + t * SCAN_WPT;
    unsigned int w[SCAN_WPT];
    if (wbase + SCAN_WPT <= nwords) {
        const uint4* q = reinterpret_cast<const uint4*>(bytemap) + 2ll * wbase;
#pragma unroll
        for (int k = 0; k < SCAN_WPT; ++k)
            w[k] = pack_word(q[2 * k], q[2 * k + 1]);
    } else {
        for (int k = 0; k < SCAN_WPT; ++k) {
            unsigned int wv = 0;
            if (wbase + k < nwords)
                for (int j = 0; j < 32; ++j)
                    wv |= (unsigned)(bytemap[32 * (wbase + k) + j]) << j;
            w[k] = wv;
        }
    }
    unsigned int s = 0;
#pragma unroll
    for (int k = 0; k < SCAN_WPT; ++k) s += __popc(w[k]);
    unsigned int x = s;
#pragma unroll
    for (int d = 1; d < 64; d <<= 1) {
        unsigned int y = __shfl_up(x, d);
        if ((t & 63) >= d) x += y;
    }
    __shared__ unsigned int ws[SCAN_T / 64];
    if ((t & 63) == 63) ws[t >> 6] = x;
    __syncthreads();
    unsigned int run = bsums[blockIdx.x] + x - s;     // exclusive across grid
    for (int wv = 0; wv < (t >> 6); ++wv) run += ws[wv];
#pragma unroll
    for (int k = 0; k < SCAN_WPT; ++k) {
        int widx = wbase + k;
        if (widx >= nwords) break;
        bits[widx]     = w[k];
        wordscan[widx] = run;
        run += __popc(w[k]);
    }
}

// ------------- pillar_indices emit: one thread per cell ---------------------
// Compaction order == cell order, so consecutive active lanes write
// consecutive 12-B rows -> dense, nearly coalesced stores.
__global__ __launch_bounds__(256) void pqag_emit(
    const unsigned int* __restrict__ bits,
    const unsigned int* __restrict__ wordscan, int ncells,
    float* __restrict__ pillar_out)
{
    int cell = blockIdx.x * 256 + threadIdx.x;
    if (cell >= ncells) return;
    unsigned int word = bits[cell >> 5];
    int bit = cell & 31;
    if ((word >> bit) & 1u) {
        unsigned int pid = wordscan[cell >> 5] + __popc(word & ((1u << bit) - 1u));
        int bidx = cell / HWG;
        int rem  = cell - bidx * HWG;
        int hy   = rem / WG;
        int wx   = rem - hy * WG;
        float* row = pillar_out + 3ull * pid;
        __builtin_nontemporal_store((float)bidx, row + 0);
        __builtin_nontemporal_store((float)hy,   row + 1);
        __builtin_nontemporal_store((float)wx,   row + 2);
    }
}

// ------------- per-point: pid gather + feature assembly ---------------------
constexpr int PT_T = 256;
__global__ __launch_bounds__(PT_T) void pqag_point(
    const int* __restrict__ xy, const int* __restrict__ cnt, int batch,
    const float* __restrict__ feats, int N,
    const unsigned int* __restrict__ bits,
    const unsigned int* __restrict__ wordscan,
    float* __restrict__ ppi_out, float* __restrict__ feat_out)
{
    __shared__ float lds[PT_T][19];   // pad 18 -> 19: gcd(19,32)=1, conflict-free
    int t = threadIdx.x;
    int blockBase = blockIdx.x * PT_T;
    int i = blockBase + t;
    int nvalid = N - blockBase; if (nvalid > PT_T) nvalid = PT_T;

    if (t < nvalid) {
        int2 p = reinterpret_cast<const int2*>(xy)[i];
        int b = 0, acc = 0;
        for (int k = 0; k < batch - 1; ++k) { acc += cnt[k]; b += (i >= acc) ? 1 : 0; }
        int flat = (b * HG + p.y) * WG + p.x;
        int widx = flat >> 5, bit = flat & 31;
        unsigned int pid = wordscan[widx] + __popc(bits[widx] & ((1u << bit) - 1u));
        __builtin_nontemporal_store((float)pid, ppi_out + i);

        const f32x4* fr = reinterpret_cast<const f32x4*>(feats + 16ll * i);
        f32x4 f0 = __builtin_nontemporal_load(fr + 0);
        f32x4 f1 = __builtin_nontemporal_load(fr + 1);
        f32x4 f2 = __builtin_nontemporal_load(fr + 2);
        f32x4 f3 = __builtin_nontemporal_load(fr + 3);
        float cx = (float)p.x * PIL + XOFF;
        float cy = (float)p.y * PIL + YOFF;
        lds[t][0]  = f0.x - cx;  lds[t][1]  = f0.y - cy;
        lds[t][2]  = f0.x;  lds[t][3]  = f0.y;  lds[t][4]  = f0.z;  lds[t][5]  = f0.w;
        lds[t][6]  = f1.x;  lds[t][7]  = f1.y;  lds[t][8]  = f1.z;  lds[t][9]  = f1.w;
        lds[t][10] = f2.x;  lds[t][11] = f2.y;  lds[t][12] = f2.z;  lds[t][13] = f2.w;
        lds[t][14] = f3.x;  lds[t][15] = f3.y;  lds[t][16] = f3.z;  lds[t][17] = f3.w;
    }
    __syncthreads();

    // coalesced streaming write of nvalid*18 contiguous floats
    float* dst = feat_out + 18ll * blockBase;
    int total = nvalid * 18;
    for (int j = t; j < total; j += PT_T) {
        int p = j / 18;
        int c = j - p * 18;
        __builtin_nontemporal_store(lds[p][c], dst + j);
    }
}

} // anonymous namespace

extern "C" void kernel_launch(void* const* d_in, const int* in_sizes, int n_in,
                              void* d_out, int out_size, void* d_ws, size_t ws_size,
                              hipStream_t stream)
{
    const int*   xy    = (const int*)d_in[0];
    const int*   cnt   = (const int*)d_in[1];
    const float* feats = (const float*)d_in[2];

    int N     = in_sizes[0] / 2;
    int batch = in_sizes[1];
    int ncells = batch * HWG;                        // 8,294,400 for batch=4
    int nwords = ncells / 32;                        // 259,200 (HWG % 32 == 0)
    long long P = (out_size - 19ll * N) / 3;         // out = 3P + N + 18N

    unsigned char* bytemap  = (unsigned char*)d_ws;
    unsigned int*  bits     = (unsigned int*)(bytemap + ncells);  // ncells %16==0
    unsigned int*  wordscan = bits + nwords;
    unsigned int*  bsums    = wordscan + nwords;

    float* pillar_out = (float*)d_out;
    float* ppi_out    = pillar_out + 3ll * P;
    float* feat_out   = ppi_out + N;

    (void)hipMemsetAsync(bytemap, 0, (size_t)ncells, stream);

    int nb_pts = (N + 255) / 256;
    pqag_scatter<<<nb_pts, 256, 0, stream>>>(xy, cnt, batch, N, bytemap);

    int nb_scan = (nwords + SCAN_CHUNK - 1) / SCAN_CHUNK;   // 254 (<=256 for scan_b)
    pqag_scan_a<<<nb_scan, SCAN_T, 0, stream>>>(bytemap, nwords, bsums);
    pqag_scan_b<<<1, SCAN_T, 0, stream>>>(bsums, nb_scan);
    pqag_scan_c<<<nb_scan, SCAN_T, 0, stream>>>(bytemap, nwords, bsums, bits, wordscan);

    int nb_emit = (ncells + 255) / 256;
    pqag_emit<<<nb_emit, 256, 0, stream>>>(bits, wordscan, ncells, pillar_out);

    pqag_point<<<nb_pts, PT_T, 0, stream>>>(xy, cnt, batch, feats, N, bits, wordscan,
                                            ppi_out, feat_out);
}

// Round 4
// 337.466 us; speedup vs baseline: 1.1184x; 1.0599x over previous
//
#include <hip/hip_runtime.h>

namespace {

typedef float f32x4 __attribute__((ext_vector_type(4)));

constexpr int   HG  = 1440;
constexpr int   WG  = 1440;
constexpr int   HWG = HG * WG;                       // 2,073,600 cells per batch
constexpr float PIL = 0.075f;
constexpr float XOFF = (float)(0.075 / 2.0 - 54.0);  // -53.9625
constexpr float YOFF = XOFF;

constexpr int SCAN_T    = 256;
constexpr int SCAN_WPT  = 4;
constexpr int SCAN_CHUNK = SCAN_T * SCAN_WPT;        // 1024 words / block

// exact per-byte (byte == 0x01) detector, carry-free across bytes:
// returns 0x80 in each byte lane where that byte equals 0x01, for ANY input.
__device__ inline unsigned eq1_msb(unsigned w) {
    unsigned t1 = (w & 0x7F7F7F7Fu) ^ 0x01010101u;
    return ~((t1 + 0x7F7F7F7Fu) | t1 | w) & 0x80808080u;
}
// 4 occupancy bytes -> 4 bits (byte j -> bit j); no carries in the multiply.
__device__ inline unsigned nib4(unsigned w) {
    return (((eq1_msb(w) >> 7) * 0x01020408u) >> 24) & 0xFu;
}
__device__ inline unsigned pack_word(uint4 a, uint4 b) {
    return  nib4(a.x)        | nib4(a.y) << 4  | nib4(a.z) << 8  | nib4(a.w) << 12
          | nib4(b.x) << 16  | nib4(b.y) << 20 | nib4(b.z) << 24 | nib4(b.w) << 28;
}

// ------------- scatter: mark occupied cells with plain byte stores ----------
__global__ __launch_bounds__(256) void pqag_scatter(
    const int* __restrict__ xy, const int* __restrict__ cnt, int batch, int N,
    unsigned char* __restrict__ bytemap)
{
    int i = blockIdx.x * 256 + threadIdx.x;
    if (i >= N) return;
    int2 p = reinterpret_cast<const int2*>(xy)[i];
    int b = 0, acc = 0;
    for (int k = 0; k < batch - 1; ++k) { acc += cnt[k]; b += (i >= acc) ? 1 : 0; }
    int flat = (b * HG + p.y) * WG + p.x;
    bytemap[flat] = 1;
}

// ------------- scan pass A: per-block occupied-cell counts ------------------
__global__ __launch_bounds__(SCAN_T) void pqag_scan_a(
    const unsigned char* __restrict__ bytemap, int nwords,
    unsigned int* __restrict__ bsums)
{
    int t = threadIdx.x;
    int wbase = blockIdx.x * SCAN_CHUNK + t * SCAN_WPT;
    unsigned int s = 0;
    if (wbase + SCAN_WPT <= nwords) {
        const uint4* q = reinterpret_cast<const uint4*>(bytemap) + 2ll * wbase;
#pragma unroll
        for (int k = 0; k < 2 * SCAN_WPT; ++k) {
            uint4 v = q[k];
            s += __popc(eq1_msb(v.x)) + __popc(eq1_msb(v.y))
               + __popc(eq1_msb(v.z)) + __popc(eq1_msb(v.w));
        }
    } else {
        for (int w = wbase; w < nwords && w < wbase + SCAN_WPT; ++w)
            for (int j = 0; j < 32; ++j) s += (bytemap[32 * w + j] == 1);
    }
#pragma unroll
    for (int d = 32; d > 0; d >>= 1) s += __shfl_down(s, d);
    __shared__ unsigned int red[SCAN_T / 64];
    if ((t & 63) == 0) red[t >> 6] = s;
    __syncthreads();
    if (t == 0) {
        unsigned int tot = 0;
        for (int w = 0; w < SCAN_T / 64; ++w) tot += red[w];
        bsums[blockIdx.x] = tot;
    }
}

// ------ scan pass C (with fused B): word exclusive scan over the grid -------
// Each block re-derives the exclusive scan of the (<=256) raw block sums
// itself (1 KB, L2-hit) -> no separate scan_b dispatch.
__global__ __launch_bounds__(SCAN_T) void pqag_scan_cb(
    const unsigned char* __restrict__ bytemap, int nwords,
    const unsigned int* __restrict__ bsums, int nb,
    unsigned int* __restrict__ bits,
    unsigned int* __restrict__ wordscan)
{
    int t = threadIdx.x;
    __shared__ unsigned int sblk;                 // scanned bsums[blockIdx.x]
    __shared__ unsigned int ws[SCAN_T / 64];

    if (t < 64) {                                  // wave 0: scan raw block sums
        int base4 = t * 4;
        unsigned int b[4];
#pragma unroll
        for (int k = 0; k < 4; ++k)
            b[k] = (base4 + k < nb) ? bsums[base4 + k] : 0u;
        unsigned int tot = b[0] + b[1] + b[2] + b[3];
        unsigned int inc = tot;
#pragma unroll
        for (int d = 1; d < 64; d <<= 1) {
            unsigned int y = __shfl_up(inc, d);
            if (t >= d) inc += y;
        }
        unsigned int excl = inc - tot;
        if (t == (blockIdx.x >> 2)) {
            unsigned int v = excl;
            for (int k = 0; k < (blockIdx.x & 3); ++k) v += b[k];
            sblk = v;
        }
    }

    int wbase = blockIdx.x * SCAN_CHUNK + t * SCAN_WPT;
    unsigned int w[SCAN_WPT];
    if (wbase + SCAN_WPT <= nwords) {
        const uint4* q = reinterpret_cast<const uint4*>(bytemap) + 2ll * wbase;
#pragma unroll
        for (int k = 0; k < SCAN_WPT; ++k)
            w[k] = pack_word(q[2 * k], q[2 * k + 1]);
    } else {
        for (int k = 0; k < SCAN_WPT; ++k) {
            unsigned int wv = 0;
            if (wbase + k < nwords)
                for (int j = 0; j < 32; ++j)
                    wv |= (unsigned)(bytemap[32 * (wbase + k) + j] == 1) << j;
            w[k] = wv;
        }
    }
    unsigned int s = 0;
#pragma unroll
    for (int k = 0; k < SCAN_WPT; ++k) s += __popc(w[k]);
    unsigned int x = s;
#pragma unroll
    for (int d = 1; d < 64; d <<= 1) {
        unsigned int y = __shfl_up(x, d);
        if ((t & 63) >= d) x += y;
    }
    if ((t & 63) == 63) ws[t >> 6] = x;
    __syncthreads();
    unsigned int run = sblk + x - s;
    for (int wv = 0; wv < (t >> 6); ++wv) run += ws[wv];
#pragma unroll
    for (int k = 0; k < SCAN_WPT; ++k) {
        int widx = wbase + k;
        if (widx >= nwords) break;
        bits[widx]     = w[k];
        wordscan[widx] = run;
        run += __popc(w[k]);
    }
}

// -------- per-point pid + features, with fused pillar_indices emit ----------
constexpr int PT_T = 256;
__global__ __launch_bounds__(PT_T) void pqag_point_emit(
    const int* __restrict__ xy, const int* __restrict__ cnt, int batch,
    const float* __restrict__ feats, int N,
    const unsigned int* __restrict__ bits,
    const unsigned int* __restrict__ wordscan,
    float* __restrict__ ppi_out, float* __restrict__ feat_out, int aligned16,
    int ncells, float* __restrict__ pillar_out)
{
    __shared__ float lds[PT_T * 18];               // flat, in output order
    int t = threadIdx.x;
    int blockBase = blockIdx.x * PT_T;
    int i = blockBase + t;
    int nvalid = N - blockBase; if (nvalid > PT_T) nvalid = PT_T;

    if (t < nvalid) {
        int2 p = reinterpret_cast<const int2*>(xy)[i];
        int b = 0, acc = 0;
        for (int k = 0; k < batch - 1; ++k) { acc += cnt[k]; b += (i >= acc) ? 1 : 0; }
        int flat = (b * HG + p.y) * WG + p.x;
        int widx = flat >> 5, bit = flat & 31;
        unsigned int pid = wordscan[widx] + __popc(bits[widx] & ((1u << bit) - 1u));
        __builtin_nontemporal_store((float)pid, ppi_out + i);

        const f32x4* fr = reinterpret_cast<const f32x4*>(feats + 16ll * i);
        f32x4 f0 = __builtin_nontemporal_load(fr + 0);
        f32x4 f1 = __builtin_nontemporal_load(fr + 1);
        f32x4 f2 = __builtin_nontemporal_load(fr + 2);
        f32x4 f3 = __builtin_nontemporal_load(fr + 3);
        float cx = (float)p.x * PIL + XOFF;
        float cy = (float)p.y * PIL + YOFF;
        float* r = &lds[t * 18];
        r[0]  = f0.x - cx;  r[1]  = f0.y - cy;
        r[2]  = f0.x;  r[3]  = f0.y;  r[4]  = f0.z;  r[5]  = f0.w;
        r[6]  = f1.x;  r[7]  = f1.y;  r[8]  = f1.z;  r[9]  = f1.w;
        r[10] = f2.x;  r[11] = f2.y;  r[12] = f2.z;  r[13] = f2.w;
        r[14] = f3.x;  r[15] = f3.y;  r[16] = f3.z;  r[17] = f3.w;
    }
    __syncthreads();

    // coalesced streaming write of nvalid*18 contiguous floats
    float* dst = feat_out + 18ll * blockBase;
    int total = nvalid * 18;
    if (aligned16) {
        int nq = total >> 2;
        for (int j = t; j < nq; j += PT_T) {
            f32x4 v = *reinterpret_cast<f32x4*>(&lds[4 * j]);
            __builtin_nontemporal_store(v, reinterpret_cast<f32x4*>(dst) + j);
        }
        for (int j = (nq << 2) + t; j < total; j += PT_T)
            __builtin_nontemporal_store(lds[j], dst + j);
    } else {
        for (int j = t; j < total; j += PT_T)
            __builtin_nontemporal_store(lds[j], dst + j);
    }

    // fused pillar_indices emit: grid-stride over cells (bits/wordscan L2-hot)
    int stride = gridDim.x * PT_T;
    for (int cell = blockBase + t; cell < ncells; cell += stride) {
        unsigned int word = bits[cell >> 5];
        int bit = cell & 31;
        if ((word >> bit) & 1u) {
            unsigned int pid = wordscan[cell >> 5] + __popc(word & ((1u << bit) - 1u));
            int bidx = cell / HWG;
            int rem  = cell - bidx * HWG;
            int hy   = rem / WG;
            int wx   = rem - hy * WG;
            float* row = pillar_out + 3ull * pid;
            __builtin_nontemporal_store((float)bidx, row + 0);
            __builtin_nontemporal_store((float)hy,   row + 1);
            __builtin_nontemporal_store((float)wx,   row + 2);
        }
    }
}

} // anonymous namespace

extern "C" void kernel_launch(void* const* d_in, const int* in_sizes, int n_in,
                              void* d_out, int out_size, void* d_ws, size_t ws_size,
                              hipStream_t stream)
{
    const int*   xy    = (const int*)d_in[0];
    const int*   cnt   = (const int*)d_in[1];
    const float* feats = (const float*)d_in[2];

    int N     = in_sizes[0] / 2;
    int batch = in_sizes[1];
    int ncells = batch * HWG;                        // 8,294,400 for batch=4
    int nwords = ncells / 32;                        // 259,200 (HWG % 32 == 0)
    long long P = (out_size - 19ll * N) / 3;         // out = 3P + N + 18N

    unsigned char* bytemap  = (unsigned char*)d_ws;
    unsigned int*  bits     = (unsigned int*)(bytemap + ncells);  // ncells %16==0
    unsigned int*  wordscan = bits + nwords;
    unsigned int*  bsums    = wordscan + nwords;

    float* pillar_out = (float*)d_out;
    float* ppi_out    = pillar_out + 3ll * P;
    float* feat_out   = ppi_out + N;
    int aligned16 = (((3ll * P + N) & 3) == 0) ? 1 : 0;

    (void)hipMemsetAsync(bytemap, 0, (size_t)ncells, stream);

    int nb_pts = (N + 255) / 256;
    pqag_scatter<<<nb_pts, 256, 0, stream>>>(xy, cnt, batch, N, bytemap);

    int nb_scan = (nwords + SCAN_CHUNK - 1) / SCAN_CHUNK;   // 254 (<=256)
    pqag_scan_a<<<nb_scan, SCAN_T, 0, stream>>>(bytemap, nwords, bsums);
    pqag_scan_cb<<<nb_scan, SCAN_T, 0, stream>>>(bytemap, nwords, bsums, nb_scan,
                                                 bits, wordscan);

    pqag_point_emit<<<nb_pts, PT_T, 0, stream>>>(xy, cnt, batch, feats, N,
                                                 bits, wordscan, ppi_out, feat_out,
                                                 aligned16, ncells, pillar_out);
}